// Round 12
// baseline (141.938 us; speedup 1.0000x reference)
//
#include <hip/hip_runtime.h>
#include <hip/hip_bf16.h>
#include <stdint.h>

#define NROW 4096
#define DIM  512
#define BM   128
#define BN   128
#define BKE  128                 // K elements per round (fp8 bytes)
#define NKT  (DIM / BKE)         // 4 rounds
#define PANEL_KT (BM * BKE)      // 16384 B staged per panel per round
#define NTILES (NROW / BM)       // 32
#define NBLK  (NTILES * (NTILES + 1) / 2)   // 528

typedef __attribute__((ext_vector_type(4))) float floatx4;  // MFMA 16x16 C/D

typedef const __attribute__((address_space(1))) void gvoid_t;
typedef __attribute__((address_space(3))) void       svoid_t;

// ctrl layout (ints): [0..3] = domain boundaries b[4]; [4..6] = scatter ctrs
__global__ __launch_bounds__(256) void setup_kernel(
    const int* __restrict__ ds, int* __restrict__ ctrl,
    float* __restrict__ out)
{
    __shared__ int hist[3];
    const int tid = threadIdx.x;
    if (tid < 3) hist[tid] = 0;
    __syncthreads();
    int c0 = 0, c1 = 0, c2 = 0;
    for (int i = tid; i < NROW; i += 256) {
        const int d = ds[i];
        c0 += (d == 0); c1 += (d == 1); c2 += (d == 2);
    }
    if (c0) atomicAdd(&hist[0], c0);
    if (c1) atomicAdd(&hist[1], c1);
    if (c2) atomicAdd(&hist[2], c2);
    __syncthreads();
    if (tid == 0) {
        const int n0 = hist[0], n1 = hist[1];
        ctrl[0] = 0; ctrl[1] = n0; ctrl[2] = n0 + n1; ctrl[3] = NROW;
        ctrl[4] = 0; ctrl[5] = n0; ctrl[6] = n0 + n1;   // scatter counters
        out[0] = 0.f; out[1] = 0.f;
    }
}

// Domain-sorted, pre-swizzled fp8 layout (R10 geometry keyed on permuted
// row nr): slab (kt=k/128, G=nr/8) of 8 rows x 128 B; logical 8-B subchunk
// c (0..15) at phys p8 = c ^ (nr & 15).  meta[nr] = {sq, bits(y*4+ds)}.
__global__ __launch_bounds__(256) void prep_kernel(
    const float* __restrict__ X, const int* __restrict__ ds,
    const int* __restrict__ y, unsigned char* __restrict__ Xq,
    float2* __restrict__ meta, int* __restrict__ ctrl)
{
    const int wave = threadIdx.x >> 6;
    const int lane = threadIdx.x & 63;
    const int row  = blockIdx.x * 4 + wave;
    const int d    = ds[row];
    int nr0 = 0;
    if (lane == 0) nr0 = atomicAdd(&ctrl[4 + d], 1);   // permuted slot
    const int nr = __shfl(nr0, 0);

    const float4* xr = (const float4*)(X + (size_t)row * DIM);
    float4 v0 = xr[2 * lane];                    // floats 8*lane .. +3
    float4 v1 = xr[2 * lane + 1];                // floats 8*lane+4 .. +7
    float s = v0.x*v0.x + v0.y*v0.y + v0.z*v0.z + v0.w*v0.w
            + v1.x*v1.x + v1.y*v1.y + v1.z*v1.z + v1.w*v1.w;
    int q0 = __builtin_amdgcn_cvt_pk_fp8_f32(v0.x, v0.y, 0, false);
    q0     = __builtin_amdgcn_cvt_pk_fp8_f32(v0.z, v0.w, q0, true);
    int q1 = __builtin_amdgcn_cvt_pk_fp8_f32(v1.x, v1.y, 0, false);
    q1     = __builtin_amdgcn_cvt_pk_fp8_f32(v1.z, v1.w, q1, true);
    const int kt = lane >> 4;                    // k/128
    const int c  = lane & 15;                    // logical 8-B subchunk
    const int p8 = c ^ (nr & 15);
    *(uint2*)(Xq + ((size_t)(kt * 512 + (nr >> 3)) * 8 + (nr & 7)) * 128
              + p8 * 8) = make_uint2((unsigned)q0, (unsigned)q1);
    #pragma unroll
    for (int off = 32; off; off >>= 1) s += __shfl_xor(s, off);
    if (lane == 0)
        meta[nr] = make_float2(s, __int_as_float(y[row] * 4 + d));
}

// R10 structure (best measured) + domain-skip: triangular 128x128 tiles on
// domain-sorted rows; tiles fully inside one domain interval have an
// all-false mask and exit before staging (~29% of blocks).
__global__ __launch_bounds__(512, 4) void ccsa_kernel(
    const unsigned char* __restrict__ Xq, const float2* __restrict__ meta,
    const int* __restrict__ ctrl,
    const int* __restrict__ ncls, const int* __restrict__ ndom,
    float* __restrict__ out)
{
    __shared__ __align__(16) unsigned char As[2 * PANEL_KT];  // 32 KB
    __shared__ __align__(16) unsigned char Bs[2 * PANEL_KT];  // 32 KB
    __shared__ float red[16];

    // scrambled triangular decode (97 coprime to 528 spreads skip-blocks)
    const int t = (blockIdx.x * 97) % NBLK;
    int r = (int)((sqrtf(8.0f * (float)t + 1.0f) - 1.0f) * 0.5f);
    while ((r + 1) * (r + 2) / 2 <= t) ++r;
    while (r * (r + 1) / 2 > t) --r;
    const int bj_t = r;
    const int bi_t = t - r * (r + 1) / 2;
    const bool diag = (bi_t == bj_t);
    const int bm0 = bi_t * BM;
    const int bn0 = bj_t * BN;

    // domain-skip: if both tile ranges sit inside one domain, no pair has
    // ds_i != ds_j -> zero contribution -> exit before any staging.
    {
        const int b1 = ctrl[1], b2 = ctrl[2];
        int domr = -1, domc = -2;
        if (bm0 + BM <= b1) domr = 0;
        else if (bm0 >= b1 && bm0 + BM <= b2) domr = 1;
        else if (bm0 >= b2) domr = 2;
        if (bn0 + BN <= b1) domc = 0;
        else if (bn0 >= b1 && bn0 + BN <= b2) domc = 1;
        else if (bn0 >= b2) domc = 2;
        if (domr >= 0 && domr == domc) return;
    }

    const int GA = bm0 >> 3;
    const int GB = bn0 >> 3;

    const int tid    = threadIdx.x;
    const int wave   = tid >> 6;
    const int lane   = tid & 63;
    const int warp_m = wave >> 2;       // 0..1 : 64-row band
    const int warp_n = wave & 3;        // 0..3 : 32-col band
    const int m15    = lane & 15;
    const int quad   = lane >> 4;

    // j-side metadata, loop-invariant
    float sqj[2]; int yj[2], dj[2];
    #pragma unroll
    for (int tn = 0; tn < 2; ++tn) {
        const float2 mj = meta[bn0 + warp_n * 32 + tn * 16 + m15];
        sqj[tn] = mj.x;
        const int ydj = __float_as_int(mj.y);
        dj[tn] = ydj & 3; yj[tn] = ydj >> 2;
    }

    floatx4 acc[4][2];
    #pragma unroll
    for (int a = 0; a < 4; ++a)
        #pragma unroll
        for (int b = 0; b < 2; ++b)
            acc[a][b] = (floatx4){0.f, 0.f, 0.f, 0.f};

    const unsigned char* Bb = diag ? As : Bs;   // diag: A-tile == B-tile

    #define STAGE(buf, kt)                                                    \
        do {                                                                  \
            const unsigned char* srcA =                                       \
                Xq + (size_t)((kt) * 512 + GA) * 1024;                        \
            __builtin_amdgcn_global_load_lds(                                 \
                (gvoid_t*)(srcA + tid * 16),                                  \
                (svoid_t*)(&As[(buf) * PANEL_KT + tid * 16]), 16, 0, 0);      \
            __builtin_amdgcn_global_load_lds(                                 \
                (gvoid_t*)(srcA + 8192 + tid * 16),                           \
                (svoid_t*)(&As[(buf) * PANEL_KT + 8192 + tid * 16]),          \
                16, 0, 0);                                                    \
            if (!diag) {                                                      \
                const unsigned char* srcB =                                   \
                    Xq + (size_t)((kt) * 512 + GB) * 1024;                    \
                __builtin_amdgcn_global_load_lds(                             \
                    (gvoid_t*)(srcB + tid * 16),                              \
                    (svoid_t*)(&Bs[(buf) * PANEL_KT + tid * 16]), 16, 0, 0);  \
                __builtin_amdgcn_global_load_lds(                             \
                    (gvoid_t*)(srcB + 8192 + tid * 16),                       \
                    (svoid_t*)(&Bs[(buf) * PANEL_KT + 8192 + tid * 16]),      \
                    16, 0, 0);                                                \
            }                                                                 \
        } while (0)

    // frag rows (panel-local); row&15 == m15 for all -> swz = m15
    const int rla0 = (warp_m * 64 +  0 + m15) * 128;
    const int rla1 = (warp_m * 64 + 16 + m15) * 128;
    const int rla2 = (warp_m * 64 + 32 + m15) * 128;
    const int rla3 = (warp_m * 64 + 48 + m15) * 128;
    const int rlb0 = (warp_n * 32 +  0 + m15) * 128;
    const int rlb1 = (warp_n * 32 + 16 + m15) * 128;

    STAGE(0, 0);
    for (int kt = 0; kt < NKT; ++kt) {
        const int cur = kt & 1;
        __syncthreads();                      // drains prev-phase loads
        if (kt + 1 < NKT) STAGE(cur ^ 1, kt + 1);
        const int cb = cur * PANEL_KT;

        #pragma unroll
        for (int s = 0; s < 4; ++s) {         // four K=32 steps per round
            const int ph = ((s * 4 + quad) ^ m15) * 8;   // un-swizzle, bytes
            const long a0 = *(const long*)(&As[cb + rla0 + ph]);
            const long a1 = *(const long*)(&As[cb + rla1 + ph]);
            const long a2 = *(const long*)(&As[cb + rla2 + ph]);
            const long a3 = *(const long*)(&As[cb + rla3 + ph]);
            const long b0 = *(const long*)(&Bb[cb + rlb0 + ph]);
            const long b1 = *(const long*)(&Bb[cb + rlb1 + ph]);
            acc[0][0] = __builtin_amdgcn_mfma_f32_16x16x32_fp8_fp8(a0, b0, acc[0][0], 0, 0, 0);
            acc[0][1] = __builtin_amdgcn_mfma_f32_16x16x32_fp8_fp8(a0, b1, acc[0][1], 0, 0, 0);
            acc[1][0] = __builtin_amdgcn_mfma_f32_16x16x32_fp8_fp8(a1, b0, acc[1][0], 0, 0, 0);
            acc[1][1] = __builtin_amdgcn_mfma_f32_16x16x32_fp8_fp8(a1, b1, acc[1][1], 0, 0, 0);
            acc[2][0] = __builtin_amdgcn_mfma_f32_16x16x32_fp8_fp8(a2, b0, acc[2][0], 0, 0, 0);
            acc[2][1] = __builtin_amdgcn_mfma_f32_16x16x32_fp8_fp8(a2, b1, acc[2][1], 0, 0, 0);
            acc[3][0] = __builtin_amdgcn_mfma_f32_16x16x32_fp8_fp8(a3, b0, acc[3][0], 0, 0, 0);
            acc[3][1] = __builtin_amdgcn_mfma_f32_16x16x32_fp8_fp8(a3, b1, acc[3][1], 0, 0, 0);
        }
    }
    #undef STAGE

    // Epilogue: C/D map col=lane&15, row=quad*4+reg (dtype-independent)
    float sa = 0.f, ss = 0.f;
    #pragma unroll
    for (int tm = 0; tm < 4; ++tm) {
        #pragma unroll
        for (int rr = 0; rr < 4; ++rr) {
            const int i = bm0 + warp_m * 64 + tm * 16 + quad * 4 + rr;
            const float2 mi = meta[i];
            const int ydi = __float_as_int(mi.y);
            const int di = ydi & 3, yi = ydi >> 2;
            #pragma unroll
            for (int tn = 0; tn < 2; ++tn) {
                if (diag) {
                    if (di < dj[tn]) {
                        const float d2   = mi.x + sqj[tn] - 2.0f * acc[tm][tn][rr];
                        const float dist = sqrtf(fmaxf(d2, 0.f));
                        if (yi == yj[tn])     sa += dist;
                        else if (yi < yj[tn]) ss += fmaxf(0.f, 1.f - dist);
                    }
                } else {
                    // fold both orientations (dist symmetric; exactly one
                    // orientation has d_lt when ds differ)
                    if (di != dj[tn]) {
                        const float d2   = mi.x + sqj[tn] - 2.0f * acc[tm][tn][rr];
                        const float dist = sqrtf(fmaxf(d2, 0.f));
                        if (yi == yj[tn]) {
                            sa += dist;
                        } else {
                            const bool take = (di < dj[tn]) ? (yi < yj[tn])
                                                            : (yj[tn] < yi);
                            if (take) ss += fmaxf(0.f, 1.f - dist);
                        }
                    }
                }
            }
        }
    }
    #pragma unroll
    for (int off = 32; off; off >>= 1) {
        sa += __shfl_xor(sa, off);
        ss += __shfl_xor(ss, off);
    }
    if (lane == 0) { red[wave] = sa; red[8 + wave] = ss; }
    __syncthreads();
    if (tid == 0) {
        float tsa = 0.f, tss = 0.f;
        #pragma unroll
        for (int w = 0; w < 8; ++w) { tsa += red[w]; tss += red[8 + w]; }
        const int nc = *ncls, nd = *ndom;
        const float n_sa = (float)(nc * (nd * (nd - 1) / 2));
        const float n_s  = (float)((nc * (nc - 1) / 2) * (nd * (nd - 1) / 2));
        atomicAdd(out + 0, tsa * 0.5f / n_sa);
        atomicAdd(out + 1, tss * 0.5f / n_s);
    }
}

extern "C" void kernel_launch(void* const* d_in, const int* in_sizes, int n_in,
                              void* d_out, int out_size, void* d_ws, size_t ws_size,
                              hipStream_t stream) {
    (void)in_sizes; (void)n_in; (void)out_size; (void)ws_size;
    const float* X  = (const float*)d_in[0];
    const int*   ds = (const int*)d_in[1];
    const int*   y  = (const int*)d_in[2];
    const int*   nc = (const int*)d_in[3];
    const int*   nd = (const int*)d_in[4];
    float* out = (float*)d_out;

    unsigned char* Xq = (unsigned char*)d_ws;                          // 2 MB
    float2* meta = (float2*)((char*)d_ws + (size_t)NROW * DIM);        // 32 KB
    int* ctrl = (int*)((char*)d_ws + (size_t)NROW * DIM + NROW * 8);   // 28 B

    setup_kernel<<<1, 256, 0, stream>>>(ds, ctrl, out);
    prep_kernel<<<NROW / 4, 256, 0, stream>>>(X, ds, y, Xq, meta, ctrl);
    ccsa_kernel<<<NBLK, 512, 0, stream>>>(Xq, meta, ctrl, nc, nd, out);
}

// Round 13
// 91.041 us; speedup vs baseline: 1.5591x; 1.5591x over previous
//
#include <hip/hip_runtime.h>
#include <hip/hip_bf16.h>
#include <stdint.h>

#define NROW 4096
#define DIM  512
#define BM   128
#define BN   128
#define BKE  128                 // K elements per round (fp8 bytes)
#define NKT  (DIM / BKE)         // 4 rounds
#define PANEL_KT (BM * BKE)      // 16384 B staged per panel per round
#define NTILES (NROW / BM)       // 32
#define NBLK  (NTILES * (NTILES + 1) / 2)   // 528

typedef __attribute__((ext_vector_type(4))) float floatx4;  // MFMA 16x16 C/D

typedef const __attribute__((address_space(1))) void gvoid_t;
typedef __attribute__((address_space(3))) void       svoid_t;

// Atomic-free domain sort: single block, packed 3-domain prefix scan.
// 256 threads x 16 rows; counts packed 21-bit into u64; 8 Hillis-Steele
// steps.  perm[row] = stable rank of row within its domain, offset by
// domain base.  ctrl[0..3] = domain boundaries.  (R12 lesson: per-wave
// atomicAdd rank = serialized same-address chain, 49 us.)
__global__ __launch_bounds__(256) void setup_kernel(
    const int* __restrict__ ds, int* __restrict__ ctrl,
    int* __restrict__ perm, float* __restrict__ out)
{
    __shared__ unsigned long long scan[256];
    const int tid = threadIdx.x;
    int d[16];
    unsigned long long mine = 0;
    #pragma unroll
    for (int k = 0; k < 16; ++k) {
        d[k] = ds[tid * 16 + k];
        mine += 1ull << (21 * d[k]);
    }
    scan[tid] = mine;
    __syncthreads();
    for (int off = 1; off < 256; off <<= 1) {
        const unsigned long long v   = scan[tid];
        const unsigned long long add = (tid >= off) ? scan[tid - off] : 0ull;
        __syncthreads();
        scan[tid] = v + add;
        __syncthreads();
    }
    const unsigned long long tot = scan[255];
    const int n0 = (int)(tot & 0x1FFFFF);
    const int n1 = (int)((tot >> 21) & 0x1FFFFF);
    const unsigned long long excl = scan[tid] - mine;
    int run[3];
    run[0] = (int)(excl & 0x1FFFFF);
    run[1] = n0 + (int)((excl >> 21) & 0x1FFFFF);
    run[2] = n0 + n1 + (int)((excl >> 42) & 0x1FFFFF);
    #pragma unroll
    for (int k = 0; k < 16; ++k)
        perm[tid * 16 + k] = run[d[k]]++;
    if (tid == 0) {
        ctrl[0] = 0; ctrl[1] = n0; ctrl[2] = n0 + n1; ctrl[3] = NROW;
        out[0] = 0.f; out[1] = 0.f;
    }
}

// Domain-sorted, pre-swizzled fp8 layout (R10 geometry keyed on permuted
// row nr = perm[row]): slab (kt=k/128, G=nr/8) of 8 rows x 128 B; logical
// 8-B subchunk c (0..15) at phys p8 = c ^ (nr & 15).
// meta[nr] = {sq, bits(y*4+ds)}.
__global__ __launch_bounds__(256) void prep_kernel(
    const float* __restrict__ X, const int* __restrict__ ds,
    const int* __restrict__ y, const int* __restrict__ perm,
    unsigned char* __restrict__ Xq, float2* __restrict__ meta)
{
    const int wave = threadIdx.x >> 6;
    const int lane = threadIdx.x & 63;
    const int row  = blockIdx.x * 4 + wave;
    const int nr   = perm[row];          // uniform-address broadcast load

    const float4* xr = (const float4*)(X + (size_t)row * DIM);
    float4 v0 = xr[2 * lane];                    // floats 8*lane .. +3
    float4 v1 = xr[2 * lane + 1];                // floats 8*lane+4 .. +7
    float s = v0.x*v0.x + v0.y*v0.y + v0.z*v0.z + v0.w*v0.w
            + v1.x*v1.x + v1.y*v1.y + v1.z*v1.z + v1.w*v1.w;
    int q0 = __builtin_amdgcn_cvt_pk_fp8_f32(v0.x, v0.y, 0, false);
    q0     = __builtin_amdgcn_cvt_pk_fp8_f32(v0.z, v0.w, q0, true);
    int q1 = __builtin_amdgcn_cvt_pk_fp8_f32(v1.x, v1.y, 0, false);
    q1     = __builtin_amdgcn_cvt_pk_fp8_f32(v1.z, v1.w, q1, true);
    const int kt = lane >> 4;                    // k/128
    const int c  = lane & 15;                    // logical 8-B subchunk
    const int p8 = c ^ (nr & 15);
    *(uint2*)(Xq + ((size_t)(kt * 512 + (nr >> 3)) * 8 + (nr & 7)) * 128
              + p8 * 8) = make_uint2((unsigned)q0, (unsigned)q1);
    #pragma unroll
    for (int off = 32; off; off >>= 1) s += __shfl_xor(s, off);
    if (lane == 0)
        meta[nr] = make_float2(s, __int_as_float(y[row] * 4 + ds[row]));
}

// R10 structure (best measured) + domain-skip: triangular 128x128 tiles on
// domain-sorted rows; tiles fully inside one domain interval have an
// all-false mask and exit before staging (~29% of blocks).
__global__ __launch_bounds__(512, 4) void ccsa_kernel(
    const unsigned char* __restrict__ Xq, const float2* __restrict__ meta,
    const int* __restrict__ ctrl,
    const int* __restrict__ ncls, const int* __restrict__ ndom,
    float* __restrict__ out)
{
    __shared__ __align__(16) unsigned char As[2 * PANEL_KT];  // 32 KB
    __shared__ __align__(16) unsigned char Bs[2 * PANEL_KT];  // 32 KB
    __shared__ float red[16];

    // scrambled triangular decode (97 coprime to 528 spreads skip-blocks)
    const int t = (blockIdx.x * 97) % NBLK;
    int r = (int)((sqrtf(8.0f * (float)t + 1.0f) - 1.0f) * 0.5f);
    while ((r + 1) * (r + 2) / 2 <= t) ++r;
    while (r * (r + 1) / 2 > t) --r;
    const int bj_t = r;
    const int bi_t = t - r * (r + 1) / 2;
    const bool diag = (bi_t == bj_t);
    const int bm0 = bi_t * BM;
    const int bn0 = bj_t * BN;

    // domain-skip: if both tile ranges sit inside one domain interval, no
    // pair has ds_i != ds_j -> zero contribution -> exit before staging.
    {
        const int b1 = ctrl[1], b2 = ctrl[2];
        int domr = -1, domc = -2;
        if (bm0 + BM <= b1) domr = 0;
        else if (bm0 >= b1 && bm0 + BM <= b2) domr = 1;
        else if (bm0 >= b2) domr = 2;
        if (bn0 + BN <= b1) domc = 0;
        else if (bn0 >= b1 && bn0 + BN <= b2) domc = 1;
        else if (bn0 >= b2) domc = 2;
        if (domr >= 0 && domr == domc) return;
    }

    const int GA = bm0 >> 3;
    const int GB = bn0 >> 3;

    const int tid    = threadIdx.x;
    const int wave   = tid >> 6;
    const int lane   = tid & 63;
    const int warp_m = wave >> 2;       // 0..1 : 64-row band
    const int warp_n = wave & 3;        // 0..3 : 32-col band
    const int m15    = lane & 15;
    const int quad   = lane >> 4;

    // j-side metadata, loop-invariant
    float sqj[2]; int yj[2], dj[2];
    #pragma unroll
    for (int tn = 0; tn < 2; ++tn) {
        const float2 mj = meta[bn0 + warp_n * 32 + tn * 16 + m15];
        sqj[tn] = mj.x;
        const int ydj = __float_as_int(mj.y);
        dj[tn] = ydj & 3; yj[tn] = ydj >> 2;
    }

    floatx4 acc[4][2];
    #pragma unroll
    for (int a = 0; a < 4; ++a)
        #pragma unroll
        for (int b = 0; b < 2; ++b)
            acc[a][b] = (floatx4){0.f, 0.f, 0.f, 0.f};

    const unsigned char* Bb = diag ? As : Bs;   // diag: A-tile == B-tile

    #define STAGE(buf, kt)                                                    \
        do {                                                                  \
            const unsigned char* srcA =                                       \
                Xq + (size_t)((kt) * 512 + GA) * 1024;                        \
            __builtin_amdgcn_global_load_lds(                                 \
                (gvoid_t*)(srcA + tid * 16),                                  \
                (svoid_t*)(&As[(buf) * PANEL_KT + tid * 16]), 16, 0, 0);      \
            __builtin_amdgcn_global_load_lds(                                 \
                (gvoid_t*)(srcA + 8192 + tid * 16),                           \
                (svoid_t*)(&As[(buf) * PANEL_KT + 8192 + tid * 16]),          \
                16, 0, 0);                                                    \
            if (!diag) {                                                      \
                const unsigned char* srcB =                                   \
                    Xq + (size_t)((kt) * 512 + GB) * 1024;                    \
                __builtin_amdgcn_global_load_lds(                             \
                    (gvoid_t*)(srcB + tid * 16),                              \
                    (svoid_t*)(&Bs[(buf) * PANEL_KT + tid * 16]), 16, 0, 0);  \
                __builtin_amdgcn_global_load_lds(                             \
                    (gvoid_t*)(srcB + 8192 + tid * 16),                       \
                    (svoid_t*)(&Bs[(buf) * PANEL_KT + 8192 + tid * 16]),      \
                    16, 0, 0);                                                \
            }                                                                 \
        } while (0)

    // frag rows (panel-local); row&15 == m15 for all -> swz = m15
    const int rla0 = (warp_m * 64 +  0 + m15) * 128;
    const int rla1 = (warp_m * 64 + 16 + m15) * 128;
    const int rla2 = (warp_m * 64 + 32 + m15) * 128;
    const int rla3 = (warp_m * 64 + 48 + m15) * 128;
    const int rlb0 = (warp_n * 32 +  0 + m15) * 128;
    const int rlb1 = (warp_n * 32 + 16 + m15) * 128;

    STAGE(0, 0);
    for (int kt = 0; kt < NKT; ++kt) {
        const int cur = kt & 1;
        __syncthreads();                      // drains prev-phase loads
        if (kt + 1 < NKT) STAGE(cur ^ 1, kt + 1);
        const int cb = cur * PANEL_KT;

        #pragma unroll
        for (int s = 0; s < 4; ++s) {         // four K=32 steps per round
            const int ph = ((s * 4 + quad) ^ m15) * 8;   // un-swizzle, bytes
            const long a0 = *(const long*)(&As[cb + rla0 + ph]);
            const long a1 = *(const long*)(&As[cb + rla1 + ph]);
            const long a2 = *(const long*)(&As[cb + rla2 + ph]);
            const long a3 = *(const long*)(&As[cb + rla3 + ph]);
            const long b0 = *(const long*)(&Bb[cb + rlb0 + ph]);
            const long b1 = *(const long*)(&Bb[cb + rlb1 + ph]);
            acc[0][0] = __builtin_amdgcn_mfma_f32_16x16x32_fp8_fp8(a0, b0, acc[0][0], 0, 0, 0);
            acc[0][1] = __builtin_amdgcn_mfma_f32_16x16x32_fp8_fp8(a0, b1, acc[0][1], 0, 0, 0);
            acc[1][0] = __builtin_amdgcn_mfma_f32_16x16x32_fp8_fp8(a1, b0, acc[1][0], 0, 0, 0);
            acc[1][1] = __builtin_amdgcn_mfma_f32_16x16x32_fp8_fp8(a1, b1, acc[1][1], 0, 0, 0);
            acc[2][0] = __builtin_amdgcn_mfma_f32_16x16x32_fp8_fp8(a2, b0, acc[2][0], 0, 0, 0);
            acc[2][1] = __builtin_amdgcn_mfma_f32_16x16x32_fp8_fp8(a2, b1, acc[2][1], 0, 0, 0);
            acc[3][0] = __builtin_amdgcn_mfma_f32_16x16x32_fp8_fp8(a3, b0, acc[3][0], 0, 0, 0);
            acc[3][1] = __builtin_amdgcn_mfma_f32_16x16x32_fp8_fp8(a3, b1, acc[3][1], 0, 0, 0);
        }
    }
    #undef STAGE

    // Epilogue: C/D map col=lane&15, row=quad*4+reg (dtype-independent)
    float sa = 0.f, ss = 0.f;
    #pragma unroll
    for (int tm = 0; tm < 4; ++tm) {
        #pragma unroll
        for (int rr = 0; rr < 4; ++rr) {
            const int i = bm0 + warp_m * 64 + tm * 16 + quad * 4 + rr;
            const float2 mi = meta[i];
            const int ydi = __float_as_int(mi.y);
            const int di = ydi & 3, yi = ydi >> 2;
            #pragma unroll
            for (int tn = 0; tn < 2; ++tn) {
                if (diag) {
                    if (di < dj[tn]) {
                        const float d2   = mi.x + sqj[tn] - 2.0f * acc[tm][tn][rr];
                        const float dist = sqrtf(fmaxf(d2, 0.f));
                        if (yi == yj[tn])     sa += dist;
                        else if (yi < yj[tn]) ss += fmaxf(0.f, 1.f - dist);
                    }
                } else {
                    // fold both orientations (dist symmetric; exactly one
                    // orientation has d_lt when ds differ)
                    if (di != dj[tn]) {
                        const float d2   = mi.x + sqj[tn] - 2.0f * acc[tm][tn][rr];
                        const float dist = sqrtf(fmaxf(d2, 0.f));
                        if (yi == yj[tn]) {
                            sa += dist;
                        } else {
                            const bool take = (di < dj[tn]) ? (yi < yj[tn])
                                                            : (yj[tn] < yi);
                            if (take) ss += fmaxf(0.f, 1.f - dist);
                        }
                    }
                }
            }
        }
    }
    #pragma unroll
    for (int off = 32; off; off >>= 1) {
        sa += __shfl_xor(sa, off);
        ss += __shfl_xor(ss, off);
    }
    if (lane == 0) { red[wave] = sa; red[8 + wave] = ss; }
    __syncthreads();
    if (tid == 0) {
        float tsa = 0.f, tss = 0.f;
        #pragma unroll
        for (int w = 0; w < 8; ++w) { tsa += red[w]; tss += red[8 + w]; }
        const int nc = *ncls, nd = *ndom;
        const float n_sa = (float)(nc * (nd * (nd - 1) / 2));
        const float n_s  = (float)((nc * (nc - 1) / 2) * (nd * (nd - 1) / 2));
        atomicAdd(out + 0, tsa * 0.5f / n_sa);
        atomicAdd(out + 1, tss * 0.5f / n_s);
    }
}

extern "C" void kernel_launch(void* const* d_in, const int* in_sizes, int n_in,
                              void* d_out, int out_size, void* d_ws, size_t ws_size,
                              hipStream_t stream) {
    (void)in_sizes; (void)n_in; (void)out_size; (void)ws_size;
    const float* X  = (const float*)d_in[0];
    const int*   ds = (const int*)d_in[1];
    const int*   y  = (const int*)d_in[2];
    const int*   nc = (const int*)d_in[3];
    const int*   nd = (const int*)d_in[4];
    float* out = (float*)d_out;

    unsigned char* Xq = (unsigned char*)d_ws;                          // 2 MB
    float2* meta = (float2*)((char*)d_ws + (size_t)NROW * DIM);        // 32 KB
    int* ctrl = (int*)((char*)d_ws + (size_t)NROW * DIM + NROW * 8);   // 64 B
    int* perm = ctrl + 16;                                             // 16 KB

    setup_kernel<<<1, 256, 0, stream>>>(ds, ctrl, perm, out);
    prep_kernel<<<NROW / 4, 256, 0, stream>>>(X, ds, y, perm, Xq, meta);
    ccsa_kernel<<<NBLK, 512, 0, stream>>>(Xq, meta, ctrl, nc, nd, out);
}

// Round 14
// 88.596 us; speedup vs baseline: 1.6021x; 1.0276x over previous
//
#include <hip/hip_runtime.h>
#include <hip/hip_bf16.h>
#include <stdint.h>

#define NROW 4096
#define DIM  512
#define BM   128
#define BN   128
#define BKE  128                 // K elements per round (fp8 bytes)
#define NKT  (DIM / BKE)         // 4 rounds
#define PANEL_KT (BM * BKE)      // 16384 B staged per panel per round
#define NTILES (NROW / BM)       // 32
#define NBLK  (NTILES * (NTILES + 1) / 2)   // 528

typedef __attribute__((ext_vector_type(4))) float floatx4;  // MFMA 16x16 C/D

typedef const __attribute__((address_space(1))) void gvoid_t;
typedef __attribute__((address_space(3))) void       svoid_t;

// Fused setup+prep: every block runs the packed 3-domain prefix scan
// redundantly (4096 ds reads, L2-broadcast; ~1k cyc) and derives the 4
// ranks it needs -- no separate setup kernel, no extra launch gap, no
// atomics (R12 lesson).  Block 0 writes ctrl boundaries + zeroes out.
// Xq layout (R10 geometry, keyed on permuted row nr): slab (kt=k/128,
// G=nr/8) of 8 rows x 128 B; logical 8-B subchunk c (0..15) at phys
// p8 = c ^ (nr & 15).  meta[nr] = {sq, bits(y*4+ds)}.
__global__ __launch_bounds__(256) void prep_kernel(
    const float* __restrict__ X, const int* __restrict__ ds,
    const int* __restrict__ y, unsigned char* __restrict__ Xq,
    float2* __restrict__ meta, int* __restrict__ ctrl,
    float* __restrict__ out)
{
    __shared__ unsigned long long scan[256];
    __shared__ int nrs[4];
    const int tid = threadIdx.x;
    const int r0  = blockIdx.x * 4;

    // packed per-thread domain counts (21-bit x 3 in u64), 16 rows/thread
    unsigned long long mine = 0;
    #pragma unroll
    for (int k = 0; k < 16; ++k)
        mine += 1ull << (21 * ds[tid * 16 + k]);
    scan[tid] = mine;
    __syncthreads();
    for (int off = 1; off < 256; off <<= 1) {
        const unsigned long long v   = scan[tid];
        const unsigned long long add = (tid >= off) ? scan[tid - off] : 0ull;
        __syncthreads();
        scan[tid] = v + add;
        __syncthreads();
    }
    const unsigned long long tot = scan[255];
    const int n0 = (int)(tot & 0x1FFFFF);
    const int n1 = (int)((tot >> 21) & 0x1FFFFF);
    if (tid < 4) {                       // ranks for this block's 4 rows
        const int r = r0 + tid;
        const int d = ds[r];
        const int g = r >> 4;
        const unsigned long long ex = g ? scan[g - 1] : 0ull;
        int cnt = (int)((ex >> (21 * d)) & 0x1FFFFF);
        for (int i = g * 16; i < r; ++i) cnt += (ds[i] == d);
        const int base = (d == 0) ? 0 : ((d == 1) ? n0 : (n0 + n1));
        nrs[tid] = base + cnt;
    }
    if (blockIdx.x == 0 && tid == 0) {
        ctrl[1] = n0; ctrl[2] = n0 + n1;
        out[0] = 0.f; out[1] = 0.f;
    }
    __syncthreads();

    const int wave = tid >> 6;
    const int lane = tid & 63;
    const int row  = r0 + wave;
    const int nr   = nrs[wave];

    const float4* xr = (const float4*)(X + (size_t)row * DIM);
    float4 v0 = xr[2 * lane];                    // floats 8*lane .. +3
    float4 v1 = xr[2 * lane + 1];                // floats 8*lane+4 .. +7
    float s = v0.x*v0.x + v0.y*v0.y + v0.z*v0.z + v0.w*v0.w
            + v1.x*v1.x + v1.y*v1.y + v1.z*v1.z + v1.w*v1.w;
    int q0 = __builtin_amdgcn_cvt_pk_fp8_f32(v0.x, v0.y, 0, false);
    q0     = __builtin_amdgcn_cvt_pk_fp8_f32(v0.z, v0.w, q0, true);
    int q1 = __builtin_amdgcn_cvt_pk_fp8_f32(v1.x, v1.y, 0, false);
    q1     = __builtin_amdgcn_cvt_pk_fp8_f32(v1.z, v1.w, q1, true);
    const int kt = lane >> 4;                    // k/128
    const int c  = lane & 15;                    // logical 8-B subchunk
    const int p8 = c ^ (nr & 15);
    *(uint2*)(Xq + ((size_t)(kt * 512 + (nr >> 3)) * 8 + (nr & 7)) * 128
              + p8 * 8) = make_uint2((unsigned)q0, (unsigned)q1);
    #pragma unroll
    for (int off = 32; off; off >>= 1) s += __shfl_xor(s, off);
    if (lane == 0)
        meta[nr] = make_float2(s, __int_as_float(y[row] * 4 + ds[row]));
}

// R13 ccsa (best measured), unchanged: triangular 128x128 tiles on
// domain-sorted rows; tiles fully inside one domain interval exit before
// staging (~30% of blocks); fp8 16x16x32 MFMA, BKE=128 dbuf, 1-KB staging.
__global__ __launch_bounds__(512, 4) void ccsa_kernel(
    const unsigned char* __restrict__ Xq, const float2* __restrict__ meta,
    const int* __restrict__ ctrl,
    const int* __restrict__ ncls, const int* __restrict__ ndom,
    float* __restrict__ out)
{
    __shared__ __align__(16) unsigned char As[2 * PANEL_KT];  // 32 KB
    __shared__ __align__(16) unsigned char Bs[2 * PANEL_KT];  // 32 KB
    __shared__ float red[16];

    // scrambled triangular decode (97 coprime to 528 spreads skip-blocks)
    const int t = (blockIdx.x * 97) % NBLK;
    int r = (int)((sqrtf(8.0f * (float)t + 1.0f) - 1.0f) * 0.5f);
    while ((r + 1) * (r + 2) / 2 <= t) ++r;
    while (r * (r + 1) / 2 > t) --r;
    const int bj_t = r;
    const int bi_t = t - r * (r + 1) / 2;
    const bool diag = (bi_t == bj_t);
    const int bm0 = bi_t * BM;
    const int bn0 = bj_t * BN;

    // domain-skip: if both tile ranges sit inside one domain interval, no
    // pair has ds_i != ds_j -> zero contribution -> exit before staging.
    {
        const int b1 = ctrl[1], b2 = ctrl[2];
        int domr = -1, domc = -2;
        if (bm0 + BM <= b1) domr = 0;
        else if (bm0 >= b1 && bm0 + BM <= b2) domr = 1;
        else if (bm0 >= b2) domr = 2;
        if (bn0 + BN <= b1) domc = 0;
        else if (bn0 >= b1 && bn0 + BN <= b2) domc = 1;
        else if (bn0 >= b2) domc = 2;
        if (domr >= 0 && domr == domc) return;
    }

    const int GA = bm0 >> 3;
    const int GB = bn0 >> 3;

    const int tid    = threadIdx.x;
    const int wave   = tid >> 6;
    const int lane   = tid & 63;
    const int warp_m = wave >> 2;       // 0..1 : 64-row band
    const int warp_n = wave & 3;        // 0..3 : 32-col band
    const int m15    = lane & 15;
    const int quad   = lane >> 4;

    // j-side metadata, loop-invariant
    float sqj[2]; int yj[2], dj[2];
    #pragma unroll
    for (int tn = 0; tn < 2; ++tn) {
        const float2 mj = meta[bn0 + warp_n * 32 + tn * 16 + m15];
        sqj[tn] = mj.x;
        const int ydj = __float_as_int(mj.y);
        dj[tn] = ydj & 3; yj[tn] = ydj >> 2;
    }

    floatx4 acc[4][2];
    #pragma unroll
    for (int a = 0; a < 4; ++a)
        #pragma unroll
        for (int b = 0; b < 2; ++b)
            acc[a][b] = (floatx4){0.f, 0.f, 0.f, 0.f};

    const unsigned char* Bb = diag ? As : Bs;   // diag: A-tile == B-tile

    #define STAGE(buf, kt)                                                    \
        do {                                                                  \
            const unsigned char* srcA =                                       \
                Xq + (size_t)((kt) * 512 + GA) * 1024;                        \
            __builtin_amdgcn_global_load_lds(                                 \
                (gvoid_t*)(srcA + tid * 16),                                  \
                (svoid_t*)(&As[(buf) * PANEL_KT + tid * 16]), 16, 0, 0);      \
            __builtin_amdgcn_global_load_lds(                                 \
                (gvoid_t*)(srcA + 8192 + tid * 16),                           \
                (svoid_t*)(&As[(buf) * PANEL_KT + 8192 + tid * 16]),          \
                16, 0, 0);                                                    \
            if (!diag) {                                                      \
                const unsigned char* srcB =                                   \
                    Xq + (size_t)((kt) * 512 + GB) * 1024;                    \
                __builtin_amdgcn_global_load_lds(                             \
                    (gvoid_t*)(srcB + tid * 16),                              \
                    (svoid_t*)(&Bs[(buf) * PANEL_KT + tid * 16]), 16, 0, 0);  \
                __builtin_amdgcn_global_load_lds(                             \
                    (gvoid_t*)(srcB + 8192 + tid * 16),                       \
                    (svoid_t*)(&Bs[(buf) * PANEL_KT + 8192 + tid * 16]),      \
                    16, 0, 0);                                                \
            }                                                                 \
        } while (0)

    // frag rows (panel-local); row&15 == m15 for all -> swz = m15
    const int rla0 = (warp_m * 64 +  0 + m15) * 128;
    const int rla1 = (warp_m * 64 + 16 + m15) * 128;
    const int rla2 = (warp_m * 64 + 32 + m15) * 128;
    const int rla3 = (warp_m * 64 + 48 + m15) * 128;
    const int rlb0 = (warp_n * 32 +  0 + m15) * 128;
    const int rlb1 = (warp_n * 32 + 16 + m15) * 128;

    STAGE(0, 0);
    for (int kt = 0; kt < NKT; ++kt) {
        const int cur = kt & 1;
        __syncthreads();                      // drains prev-phase loads
        if (kt + 1 < NKT) STAGE(cur ^ 1, kt + 1);
        const int cb = cur * PANEL_KT;

        #pragma unroll
        for (int s = 0; s < 4; ++s) {         // four K=32 steps per round
            const int ph = ((s * 4 + quad) ^ m15) * 8;   // un-swizzle, bytes
            const long a0 = *(const long*)(&As[cb + rla0 + ph]);
            const long a1 = *(const long*)(&As[cb + rla1 + ph]);
            const long a2 = *(const long*)(&As[cb + rla2 + ph]);
            const long a3 = *(const long*)(&As[cb + rla3 + ph]);
            const long b0 = *(const long*)(&Bb[cb + rlb0 + ph]);
            const long b1 = *(const long*)(&Bb[cb + rlb1 + ph]);
            acc[0][0] = __builtin_amdgcn_mfma_f32_16x16x32_fp8_fp8(a0, b0, acc[0][0], 0, 0, 0);
            acc[0][1] = __builtin_amdgcn_mfma_f32_16x16x32_fp8_fp8(a0, b1, acc[0][1], 0, 0, 0);
            acc[1][0] = __builtin_amdgcn_mfma_f32_16x16x32_fp8_fp8(a1, b0, acc[1][0], 0, 0, 0);
            acc[1][1] = __builtin_amdgcn_mfma_f32_16x16x32_fp8_fp8(a1, b1, acc[1][1], 0, 0, 0);
            acc[2][0] = __builtin_amdgcn_mfma_f32_16x16x32_fp8_fp8(a2, b0, acc[2][0], 0, 0, 0);
            acc[2][1] = __builtin_amdgcn_mfma_f32_16x16x32_fp8_fp8(a2, b1, acc[2][1], 0, 0, 0);
            acc[3][0] = __builtin_amdgcn_mfma_f32_16x16x32_fp8_fp8(a3, b0, acc[3][0], 0, 0, 0);
            acc[3][1] = __builtin_amdgcn_mfma_f32_16x16x32_fp8_fp8(a3, b1, acc[3][1], 0, 0, 0);
        }
    }
    #undef STAGE

    // Epilogue: C/D map col=lane&15, row=quad*4+reg (dtype-independent)
    float sa = 0.f, ss = 0.f;
    #pragma unroll
    for (int tm = 0; tm < 4; ++tm) {
        #pragma unroll
        for (int rr = 0; rr < 4; ++rr) {
            const int i = bm0 + warp_m * 64 + tm * 16 + quad * 4 + rr;
            const float2 mi = meta[i];
            const int ydi = __float_as_int(mi.y);
            const int di = ydi & 3, yi = ydi >> 2;
            #pragma unroll
            for (int tn = 0; tn < 2; ++tn) {
                if (diag) {
                    if (di < dj[tn]) {
                        const float d2   = mi.x + sqj[tn] - 2.0f * acc[tm][tn][rr];
                        const float dist = sqrtf(fmaxf(d2, 0.f));
                        if (yi == yj[tn])     sa += dist;
                        else if (yi < yj[tn]) ss += fmaxf(0.f, 1.f - dist);
                    }
                } else {
                    // fold both orientations (dist symmetric; exactly one
                    // orientation has d_lt when ds differ)
                    if (di != dj[tn]) {
                        const float d2   = mi.x + sqj[tn] - 2.0f * acc[tm][tn][rr];
                        const float dist = sqrtf(fmaxf(d2, 0.f));
                        if (yi == yj[tn]) {
                            sa += dist;
                        } else {
                            const bool take = (di < dj[tn]) ? (yi < yj[tn])
                                                            : (yj[tn] < yi);
                            if (take) ss += fmaxf(0.f, 1.f - dist);
                        }
                    }
                }
            }
        }
    }
    #pragma unroll
    for (int off = 32; off; off >>= 1) {
        sa += __shfl_xor(sa, off);
        ss += __shfl_xor(ss, off);
    }
    if (lane == 0) { red[wave] = sa; red[8 + wave] = ss; }
    __syncthreads();
    if (tid == 0) {
        float tsa = 0.f, tss = 0.f;
        #pragma unroll
        for (int w = 0; w < 8; ++w) { tsa += red[w]; tss += red[8 + w]; }
        const int nc = *ncls, nd = *ndom;
        const float n_sa = (float)(nc * (nd * (nd - 1) / 2));
        const float n_s  = (float)((nc * (nc - 1) / 2) * (nd * (nd - 1) / 2));
        atomicAdd(out + 0, tsa * 0.5f / n_sa);
        atomicAdd(out + 1, tss * 0.5f / n_s);
    }
}

extern "C" void kernel_launch(void* const* d_in, const int* in_sizes, int n_in,
                              void* d_out, int out_size, void* d_ws, size_t ws_size,
                              hipStream_t stream) {
    (void)in_sizes; (void)n_in; (void)out_size; (void)ws_size;
    const float* X  = (const float*)d_in[0];
    const int*   ds = (const int*)d_in[1];
    const int*   y  = (const int*)d_in[2];
    const int*   nc = (const int*)d_in[3];
    const int*   nd = (const int*)d_in[4];
    float* out = (float*)d_out;

    unsigned char* Xq = (unsigned char*)d_ws;                          // 2 MB
    float2* meta = (float2*)((char*)d_ws + (size_t)NROW * DIM);        // 32 KB
    int* ctrl = (int*)((char*)d_ws + (size_t)NROW * DIM + NROW * 8);   // 64 B

    prep_kernel<<<NROW / 4, 256, 0, stream>>>(X, ds, y, Xq, meta, ctrl, out);
    ccsa_kernel<<<NBLK, 512, 0, stream>>>(Xq, meta, ctrl, nc, nd, out);
}